// Round 6
// baseline (642.494 us; speedup 1.0000x reference)
//
#include <hip/hip_runtime.h>
#include <math.h>

// CapsuleLayer dynamic routing, fp32 in/out. B=256, I=2048, K=8, J=10, D=16.
// R10: R9 fused cooperative kernel, but cg::grid.sync() (measured ~70us/sync
// on this platform: 453us kernel @ 5.5% VALUBusy = ~420us waiting across 6
// syncs) replaced with a custom device-scope counting barrier (~2-5us):
// threadfence + agent-scope atomic arrive + s_sleep spin on per-phase counter.
// Counters (6 x u32, 64B) zeroed via hipMemsetAsync before the launch.
// Co-residency still guaranteed by hipLaunchCooperativeKernel (512 blocks,
// 2/CU: LDS 57344B, __launch_bounds__(256,2)). R9 counters confirmed: no
// catastrophic spill (VALU work ~25us as modeled), results bit-exact.
// Round core math unchanged (mfma_f32_16x16x32_bf16, C/D col=lane&15=b,
// row=(lane>>4)*4+reg=d; round 1 packs 4 i's into K=32; j-pair uint4 p;
// vT layout [j][b][d]).
// Fallback: coop-launch error -> multi-kernel path (R6-style, ~140us).
//
// ws: bar u32[16] | vT f32[40960] | p f16[16*128*2560] | xTb bf16[I*B*K] | Wb bf16[J*I*D*K]

#define BB 256
#define II 2048
#define KK 8
#define JJ 10
#define DD 16

typedef __attribute__((ext_vector_type(4))) float f32x4;
typedef __attribute__((ext_vector_type(8))) short short8;

__device__ __forceinline__ short f2bf(float f) {
    union { float f; unsigned u; } v; v.f = f;
    unsigned r = v.u + 0x7FFFu + ((v.u >> 16) & 1u);   // RNE
    return (short)(r >> 16);
}

// ---- custom grid barrier: per-phase counter, agent scope ----
__device__ __forceinline__ void gbar(unsigned* __restrict__ bar, int phase, unsigned nblk) {
    __syncthreads();
    if (threadIdx.x == 0) {
        __threadfence();   // make prior writes visible device-wide (L2 writeback)
        __hip_atomic_fetch_add(&bar[phase], 1u, __ATOMIC_RELEASE, __HIP_MEMORY_SCOPE_AGENT);
        while (__hip_atomic_load(&bar[phase], __ATOMIC_ACQUIRE, __HIP_MEMORY_SCOPE_AGENT) < nblk)
            __builtin_amdgcn_s_sleep(1);
        __threadfence();   // invalidate stale local caches before consuming peers' data
    }
    __syncthreads();
}

// ---- staging helpers: 28 segments of 1024B per 8-i sub-chunk (20 W halves + 8 x rows) ----
// LDS layout per buffer (shorts): Wl[j][il][d][k] at j*1024+il*128+d*8 ; Xl at 10240+il*512+b*8
#define LBUF 14336   // shorts per buffer

__device__ __forceinline__ void seg_src_dst(int s, int i0, int b0,
                                            const short* __restrict__ xTb,
                                            const short* __restrict__ Wb,
                                            const short** src, int* dst) {
    if (s < 20) {
        const int j = s >> 1, h = s & 1;
        *src = Wb + ((size_t)(j * II + i0) * DD) * KK + h * 512;
        *dst = j * 1024 + h * 512;
    } else {
        const int il = s - 20;
        *src = xTb + ((size_t)(i0 + il) * BB + b0) * KK;
        *dst = 10240 + il * 512;
    }
}

// =====================  fused cooperative kernel  =====================
__global__ __launch_bounds__(256, 2) void fused_all(
    const float* __restrict__ x, const float* __restrict__ W,
    short* __restrict__ xTb, short* __restrict__ Wb,
    float* __restrict__ vT, _Float16* __restrict__ p, float* __restrict__ out,
    unsigned* __restrict__ bar)
{
    __shared__ short L[2][LBUF];
    const int t = threadIdx.x;
    const int bid = blockIdx.x;
    const unsigned NB = 512;

    // ---------- phase 0: preprocessing (3328 units over 512 blocks) ----------
    for (int u = bid; u < 3328; u += 512) {
        if (u < 1280) {
            // W fp32 [j,i,d,k] -> Wb bf16 same layout
            const int idx = u * 256 + t;
            const float4* src = (const float4*)(W + (size_t)idx * 8);
            const float4 a = src[0], b = src[1];
            short8 o;
            o[0] = f2bf(a.x); o[1] = f2bf(a.y); o[2] = f2bf(a.z); o[3] = f2bf(a.w);
            o[4] = f2bf(b.x); o[5] = f2bf(b.y); o[6] = f2bf(b.z); o[7] = f2bf(b.w);
            *(short8*)(Wb + (size_t)idx * 8) = o;
        } else {
            // x fp32 [b,i,k] -> xTb bf16 [i,b,k], LDS transpose (tile aliases L)
            float4* tile = (float4*)(&L[0][0]);
            const int bb = u - 1280;
            const int b0p = (bb >> 8) * 32, i0p = (bb & 255) * 8;
            __syncthreads();   // protect tile reuse across u iterations
            {
                const int lb = t >> 3, li = t & 7;
                const float4* src = (const float4*)(x + ((b0p + lb) * II + (i0p + li)) * KK);
                tile[li * 66 + lb * 2 + 0] = src[0];
                tile[li * 66 + lb * 2 + 1] = src[1];
            }
            __syncthreads();
            {
                const int ri = t >> 5, rb = t & 31;
                const float4 p0 = tile[ri * 66 + rb * 2 + 0];
                const float4 p1 = tile[ri * 66 + rb * 2 + 1];
                short8 o;
                o[0] = f2bf(p0.x); o[1] = f2bf(p0.y); o[2] = f2bf(p0.z); o[3] = f2bf(p0.w);
                o[4] = f2bf(p1.x); o[5] = f2bf(p1.y); o[6] = f2bf(p1.z); o[7] = f2bf(p1.w);
                *(short8*)(xTb + ((size_t)(i0p + ri) * BB + (b0p + rb)) * KK) = o;
            }
        }
    }
    gbar(bar, 0, NB);   // xTb/Wb visible device-wide

    // ---------- round geometry (R6 linear decode) ----------
    const int lane = t & 63, wv = t >> 6;
    const int col = lane & 15, q = lane >> 4;
    const int chunk = bid & 127;
    const int ytile = (bid >> 7) & 3;
    const int b0 = ytile * 64;
    const int bl = wv * 16 + col;          // b within block for this wave's tile
    const int i0 = chunk * 16;

    // ---------- initial staging for round 0 ----------
    short8 r0[7], r1[7];
#pragma unroll
    for (int n = 0; n < 7; ++n) {
        const int s = wv + n * 4;          // 4 waves interleave the 28 segments
        const short* src; int dst;
        seg_src_dst(s, i0, b0, xTb, Wb, &src, &dst);
        r0[n] = *(const short8*)(src + lane * 8);
        seg_src_dst(s, i0 + 8, b0, xTb, Wb, &src, &dst);
        r1[n] = *(const short8*)(src + lane * 8);
    }
#pragma unroll
    for (int n = 0; n < 7; ++n) {
        const int s = wv + n * 4;
        const short* src; int dst;
        seg_src_dst(s, i0, b0, xTb, Wb, &src, &dst);
        *(short8*)(&L[0][dst + lane * 8]) = r0[n];
    }
    __syncthreads();

#pragma unroll 1
    for (int r = 0; r < 3; ++r) {
        f32x4 sfrag[JJ];
#pragma unroll
        for (int j = 0; j < JJ; ++j) sfrag[j] = (f32x4){0.f, 0.f, 0.f, 0.f};

        f32x4 vfrag[JJ];
        if (r > 0) {
#pragma unroll
            for (int j = 0; j < JJ; ++j)
                vfrag[j] = *(const f32x4*)(vT + ((size_t)j * BB + b0 + bl) * DD + q * 4);
        }

#pragma unroll
        for (int sc = 0; sc < 2; ++sc) {
            const short* Lb = L[sc];
            if (r > 0) {
                for (int il = 0; il < 8; ++il) {
                    short8 A[JJ], Bf;
                    const short8 z = (short8){0, 0, 0, 0, 0, 0, 0, 0};
                    Bf = z;
#pragma unroll
                    for (int j = 0; j < JJ; ++j) A[j] = z;
                    if (q == 0) {   // kc 0..7 real, quads 1..3 stay zero (k-pad 8->32)
                        Bf = *(const short8*)(&Lb[10240 + il * 512 + bl * 8]);
#pragma unroll
                        for (int j = 0; j < JJ; ++j)
                            A[j] = *(const short8*)(&Lb[j * 1024 + il * 128 + col * 8]);
                    }
                    f32x4 U[JJ];
#pragma unroll
                    for (int j = 0; j < JJ; ++j)
                        U[j] = __builtin_amdgcn_mfma_f32_16x16x32_bf16(
                            A[j], Bf, (f32x4){0.f, 0.f, 0.f, 0.f}, 0, 0, 0);
                    float Lg[JJ];
#pragma unroll
                    for (int j = 0; j < JJ; ++j)
                        Lg[j] = vfrag[j][0] * U[j][0] + vfrag[j][1] * U[j][1]
                              + vfrag[j][2] * U[j][2] + vfrag[j][3] * U[j][3];
#pragma unroll
                    for (int j = 0; j < JJ; ++j) {   // reduce over the 4 d-quads
                        Lg[j] += __shfl_xor(Lg[j], 16, 64);
                        Lg[j] += __shfl_xor(Lg[j], 32, 64);
                    }
                    float sum = 0.f;   // |logit| is O(1): no max-subtraction needed
#pragma unroll
                    for (int j = 0; j < JJ; ++j) { Lg[j] = __expf(Lg[j]); sum += Lg[j]; }
                    const float inv = __builtin_amdgcn_rcpf(sum);
#pragma unroll
                    for (int j = 0; j < JJ; ++j) {
                        const float c = Lg[j] * inv;
#pragma unroll
                        for (int rr = 0; rr < 4; ++rr) sfrag[j][rr] += c * U[j][rr];
                    }
                }
            } else {
                // round 1: sum_i U. Pack 4 i's per MFMA: kc = q*8 + k -> i_local = q.
#pragma unroll
                for (int s = 0; s < 2; ++s) {
                    const int il = s * 4 + q;
                    const short8 Bf = *(const short8*)(&Lb[10240 + il * 512 + bl * 8]);
#pragma unroll
                    for (int j = 0; j < JJ; ++j) {
                        const short8 A = *(const short8*)(&Lb[j * 1024 + il * 128 + col * 8]);
                        sfrag[j] = __builtin_amdgcn_mfma_f32_16x16x32_bf16(A, Bf, sfrag[j], 0, 0, 0);
                    }
                }
            }
            if (sc == 0) {   // publish sub-chunk 1 (regs were loaded earlier)
#pragma unroll
                for (int n = 0; n < 7; ++n) {
                    const int s = wv + n * 4;
                    const short* src; int dst;
                    seg_src_dst(s, i0 + 8, b0, xTb, Wb, &src, &dst);
                    *(short8*)(&L[1][dst + lane * 8]) = r1[n];
                }
                __syncthreads();
            }
        }

        // epilogue: j-pair-packed fp16, 5 coalesced 16B stores per lane
        _Float16* pp = p + (((size_t)(ytile * 4 + wv) * 128 + chunk) * 5) * 512;
#pragma unroll
        for (int jp = 0; jp < 5; ++jp) {
            union { uint4 u; _Float16 h[8]; } pk;
            pk.h[0] = (_Float16)sfrag[2 * jp][0];
            pk.h[1] = (_Float16)sfrag[2 * jp][1];
            pk.h[2] = (_Float16)sfrag[2 * jp][2];
            pk.h[3] = (_Float16)sfrag[2 * jp][3];
            pk.h[4] = (_Float16)sfrag[2 * jp + 1][0];
            pk.h[5] = (_Float16)sfrag[2 * jp + 1][1];
            pk.h[6] = (_Float16)sfrag[2 * jp + 1][2];
            pk.h[7] = (_Float16)sfrag[2 * jp + 1][3];
            *(uint4*)(pp + (size_t)(jp * 64 + lane) * 8) = pk.u;
        }

        // stage next round (reads only xTb/Wb; overlaps with barrier + rs below).
        // Writes L[0] only -- L[1] is dead until next round's sc0-end publish.
        if (r < 2) {
#pragma unroll
            for (int n = 0; n < 7; ++n) {
                const int s = wv + n * 4;
                const short* src; int dst;
                seg_src_dst(s, i0, b0, xTb, Wb, &src, &dst);
                r0[n] = *(const short8*)(src + lane * 8);
                seg_src_dst(s, i0 + 8, b0, xTb, Wb, &src, &dst);
                r1[n] = *(const short8*)(src + lane * 8);
            }
#pragma unroll
            for (int n = 0; n < 7; ++n) {
                const int s = wv + n * 4;
                const short* src; int dst;
                seg_src_dst(s, i0, b0, xTb, Wb, &src, &dst);
                *(short8*)(&L[0][dst + lane * 8]) = r0[n];
            }
        }

        gbar(bar, 1 + 2 * r, NB);   // p visible device-wide

        // ---------- rs phase: 80 blocks; red[] aliases dead L[1] ----------
        if (bid < 80) {
            const int jp = bid % 5, btq = bid / 5;
            const int eg = t & 63, cgi = t >> 6;
            float (*red)[9] = (float (*)[9])(&L[1][0]);
            const _Float16* prd = p + (((size_t)btq * 128 + cgi * 32) * 5 + jp) * 512 + eg * 8;
            float sacc[8];
#pragma unroll
            for (int rr = 0; rr < 8; ++rr) sacc[rr] = 0.f;
#pragma unroll 4
            for (int ch = 0; ch < 32; ++ch) {
                union { uint4 u; _Float16 h[8]; } cv;
                cv.u = *(const uint4*)(prd + (size_t)ch * (5 * 512));
#pragma unroll
                for (int rr = 0; rr < 8; ++rr) sacc[rr] += (float)cv.h[rr];
            }
#pragma unroll
            for (int rr = 0; rr < 8; ++rr) red[t][rr] = sacc[rr];
            __syncthreads();
            if (t < 64) {
                float a[8];
#pragma unroll
                for (int rr = 0; rr < 8; ++rr)
                    a[rr] = red[t][rr] + red[t + 64][rr] + red[t + 128][rr] + red[t + 192][rr];
                const int qd = t >> 4, bc = t & 15;
                const float scale = (r == 0) ? 0.1f : 1.0f;
#pragma unroll
                for (int jj = 0; jj < 2; ++jj) {
                    const int j = jp * 2 + jj;
                    const float x0 = a[jj * 4 + 0] * scale, x1 = a[jj * 4 + 1] * scale;
                    const float x2 = a[jj * 4 + 2] * scale, x3 = a[jj * 4 + 3] * scale;
                    float ss = x0 * x0 + x1 * x1 + x2 * x2 + x3 * x3;
                    ss += __shfl_xor(ss, 16, 64);   // sum over the 4 d-quads (same bc)
                    ss += __shfl_xor(ss, 32, 64);
                    const float coef = ss / (1.f + ss) / sqrtf(ss + 1e-7f);
                    f32x4 v = {coef * x0, coef * x1, coef * x2, coef * x3};
                    if (r == 0)
                        *(f32x4*)(vT + ((size_t)j * BB + btq * 16 + bc) * DD + qd * 4) = v;
                    else if (r == 1) {
                        f32x4 o = *(f32x4*)(vT + ((size_t)j * BB + btq * 16 + bc) * DD + qd * 4);
                        o += v;
                        *(f32x4*)(vT + ((size_t)j * BB + btq * 16 + bc) * DD + qd * 4) = o;
                    } else
                        *(f32x4*)(out + ((size_t)(btq * 16 + bc) * JJ + j) * DD + qd * 4) = v;
                }
            }
        }

        if (r < 2) gbar(bar, 2 + 2 * r, NB);   // vT visible for next round's vfrag
    }
}

// =====================  multi-kernel fallback (R6-style)  =====================

__global__ __launch_bounds__(256) void pre_kernel(const float* __restrict__ x,
                                                  const float* __restrict__ W,
                                                  short* __restrict__ xTb,
                                                  short* __restrict__ Wb) {
    __shared__ float4 tile[8 * 66];
    const int t = threadIdx.x;
    const int bid = blockIdx.x;
    if (bid < 1280) {
        const int idx = bid * 256 + t;
        const float4* src = (const float4*)(W + (size_t)idx * 8);
        const float4 a = src[0], b = src[1];
        short8 o;
        o[0] = f2bf(a.x); o[1] = f2bf(a.y); o[2] = f2bf(a.z); o[3] = f2bf(a.w);
        o[4] = f2bf(b.x); o[5] = f2bf(b.y); o[6] = f2bf(b.z); o[7] = f2bf(b.w);
        *(short8*)(Wb + (size_t)idx * 8) = o;
    } else {
        const int bb = bid - 1280;
        const int b0 = (bb >> 8) * 32, i0 = (bb & 255) * 8;
        {
            const int lb = t >> 3, li = t & 7;
            const float4* src = (const float4*)(x + ((b0 + lb) * II + (i0 + li)) * KK);
            tile[li * 66 + lb * 2 + 0] = src[0];
            tile[li * 66 + lb * 2 + 1] = src[1];
        }
        __syncthreads();
        {
            const int ri = t >> 5, rb = t & 31;
            const float4 p0 = tile[ri * 66 + rb * 2 + 0];
            const float4 p1 = tile[ri * 66 + rb * 2 + 1];
            short8 o;
            o[0] = f2bf(p0.x); o[1] = f2bf(p0.y); o[2] = f2bf(p0.z); o[3] = f2bf(p0.w);
            o[4] = f2bf(p1.x); o[5] = f2bf(p1.y); o[6] = f2bf(p1.z); o[7] = f2bf(p1.w);
            *(short8*)(xTb + ((size_t)(i0 + ri) * BB + (b0 + rb)) * KK) = o;
        }
    }
}

// grid (128, 4): blockIdx.x = chunk, blockIdx.y = ytile (R6 linear decode).
template <int USE_C>
__global__ __launch_bounds__(256) void round_mfma(
    const short* __restrict__ xTb, const short* __restrict__ Wb,
    const float* __restrict__ vT, _Float16* __restrict__ p)
{
    __shared__ short L[2][LBUF];
    const int t = threadIdx.x;
    const int lane = t & 63, wv = t >> 6;
    const int col = lane & 15, q = lane >> 4;
    const int chunk = blockIdx.x;
    const int ytile = blockIdx.y;
    const int b0 = ytile * 64;
    const int bl = wv * 16 + col;
    const int i0 = chunk * 16;

    short8 r0[7], r1[7];
#pragma unroll
    for (int n = 0; n < 7; ++n) {
        const int s = wv + n * 4;
        const short* src; int dst;
        seg_src_dst(s, i0, b0, xTb, Wb, &src, &dst);
        r0[n] = *(const short8*)(src + lane * 8);
        seg_src_dst(s, i0 + 8, b0, xTb, Wb, &src, &dst);
        r1[n] = *(const short8*)(src + lane * 8);
    }
#pragma unroll
    for (int n = 0; n < 7; ++n) {
        const int s = wv + n * 4;
        const short* src; int dst;
        seg_src_dst(s, i0, b0, xTb, Wb, &src, &dst);
        *(short8*)(&L[0][dst + lane * 8]) = r0[n];
    }
    __syncthreads();

    f32x4 sfrag[JJ];
#pragma unroll
    for (int j = 0; j < JJ; ++j) sfrag[j] = (f32x4){0.f, 0.f, 0.f, 0.f};

    f32x4 vfrag[JJ];
    if (USE_C) {
#pragma unroll
        for (int j = 0; j < JJ; ++j)
            vfrag[j] = *(const f32x4*)(vT + ((size_t)j * BB + b0 + bl) * DD + q * 4);
    }

#pragma unroll
    for (int sc = 0; sc < 2; ++sc) {
        const short* Lb = L[sc];
        if (USE_C) {
            for (int il = 0; il < 8; ++il) {
                short8 A[JJ], Bf;
                const short8 z = (short8){0, 0, 0, 0, 0, 0, 0, 0};
                Bf = z;
#pragma unroll
                for (int j = 0; j < JJ; ++j) A[j] = z;
                if (q == 0) {
                    Bf = *(const short8*)(&Lb[10240 + il * 512 + bl * 8]);
#pragma unroll
                    for (int j = 0; j < JJ; ++j)
                        A[j] = *(const short8*)(&Lb[j * 1024 + il * 128 + col * 8]);
                }
                f32x4 U[JJ];
#pragma unroll
                for (int j = 0; j < JJ; ++j)
                    U[j] = __builtin_amdgcn_mfma_f32_16x16x32_bf16(
                        A[j], Bf, (f32x4){0.f, 0.f, 0.f, 0.f}, 0, 0, 0);
                float Lg[JJ];
#pragma unroll
                for (int j = 0; j < JJ; ++j)
                    Lg[j] = vfrag[j][0] * U[j][0] + vfrag[j][1] * U[j][1]
                          + vfrag[j][2] * U[j][2] + vfrag[j][3] * U[j][3];
#pragma unroll
                for (int j = 0; j < JJ; ++j) {
                    Lg[j] += __shfl_xor(Lg[j], 16, 64);
                    Lg[j] += __shfl_xor(Lg[j], 32, 64);
                }
                float sum = 0.f;
#pragma unroll
                for (int j = 0; j < JJ; ++j) { Lg[j] = __expf(Lg[j]); sum += Lg[j]; }
                const float inv = __builtin_amdgcn_rcpf(sum);
#pragma unroll
                for (int j = 0; j < JJ; ++j) {
                    const float c = Lg[j] * inv;
#pragma unroll
                    for (int rr = 0; rr < 4; ++rr) sfrag[j][rr] += c * U[j][rr];
                }
            }
        } else {
#pragma unroll
            for (int s = 0; s < 2; ++s) {
                const int il = s * 4 + q;
                const short8 Bf = *(const short8*)(&Lb[10240 + il * 512 + bl * 8]);
#pragma unroll
                for (int j = 0; j < JJ; ++j) {
                    const short8 A = *(const short8*)(&Lb[j * 1024 + il * 128 + col * 8]);
                    sfrag[j] = __builtin_amdgcn_mfma_f32_16x16x32_bf16(A, Bf, sfrag[j], 0, 0, 0);
                }
            }
        }
        if (sc == 0) {
#pragma unroll
            for (int n = 0; n < 7; ++n) {
                const int s = wv + n * 4;
                const short* src; int dst;
                seg_src_dst(s, i0 + 8, b0, xTb, Wb, &src, &dst);
                *(short8*)(&L[1][dst + lane * 8]) = r1[n];
            }
            __syncthreads();
        }
    }

    _Float16* pp = p + (((size_t)(ytile * 4 + wv) * 128 + chunk) * 5) * 512;
#pragma unroll
    for (int jp = 0; jp < 5; ++jp) {
        union { uint4 u; _Float16 h[8]; } pk;
        pk.h[0] = (_Float16)sfrag[2 * jp][0];
        pk.h[1] = (_Float16)sfrag[2 * jp][1];
        pk.h[2] = (_Float16)sfrag[2 * jp][2];
        pk.h[3] = (_Float16)sfrag[2 * jp][3];
        pk.h[4] = (_Float16)sfrag[2 * jp + 1][0];
        pk.h[5] = (_Float16)sfrag[2 * jp + 1][1];
        pk.h[6] = (_Float16)sfrag[2 * jp + 1][2];
        pk.h[7] = (_Float16)sfrag[2 * jp + 1][3];
        *(uint4*)(pp + (size_t)(jp * 64 + lane) * 8) = pk.u;
    }
}

template <int MODE>
__global__ __launch_bounds__(256) void rs_kernel(const _Float16* __restrict__ p,
                                                 float* __restrict__ vT,
                                                 float* __restrict__ out, float scale) {
    __shared__ float red[256][9];
    const int t = threadIdx.x;
    const int jp = blockIdx.x, bt = blockIdx.y;
    const int eg = t & 63, cgi = t >> 6;

    const _Float16* pp = p + (((size_t)bt * 128 + cgi * 32) * 5 + jp) * 512 + eg * 8;
    float s[8];
#pragma unroll
    for (int rr = 0; rr < 8; ++rr) s[rr] = 0.f;
#pragma unroll 4
    for (int ch = 0; ch < 32; ++ch) {
        union { uint4 u; _Float16 h[8]; } cv;
        cv.u = *(const uint4*)(pp + (size_t)ch * (5 * 512));
#pragma unroll
        for (int rr = 0; rr < 8; ++rr) s[rr] += (float)cv.h[rr];
    }
#pragma unroll
    for (int rr = 0; rr < 8; ++rr) red[t][rr] = s[rr];
    __syncthreads();
    if (t < 64) {
        float a[8];
#pragma unroll
        for (int rr = 0; rr < 8; ++rr)
            a[rr] = red[t][rr] + red[t + 64][rr] + red[t + 128][rr] + red[t + 192][rr];
        const int qd = t >> 4, bc = t & 15;
#pragma unroll
        for (int jj = 0; jj < 2; ++jj) {
            const int j = jp * 2 + jj;
            const float x0 = a[jj * 4 + 0] * scale, x1 = a[jj * 4 + 1] * scale;
            const float x2 = a[jj * 4 + 2] * scale, x3 = a[jj * 4 + 3] * scale;
            float ss = x0 * x0 + x1 * x1 + x2 * x2 + x3 * x3;
            ss += __shfl_xor(ss, 16, 64);
            ss += __shfl_xor(ss, 32, 64);
            const float coef = ss / (1.f + ss) / sqrtf(ss + 1e-7f);
            f32x4 v = {coef * x0, coef * x1, coef * x2, coef * x3};
            if (MODE == 0)
                *(f32x4*)(vT + ((size_t)j * BB + bt * 16 + bc) * DD + qd * 4) = v;
            if (MODE == 1) {
                f32x4 o = *(f32x4*)(vT + ((size_t)j * BB + bt * 16 + bc) * DD + qd * 4);
                o += v;
                *(f32x4*)(vT + ((size_t)j * BB + bt * 16 + bc) * DD + qd * 4) = o;
            }
            if (MODE == 2)
                *(f32x4*)(out + ((size_t)(bt * 16 + bc) * JJ + j) * DD + qd * 4) = v;
        }
    }
}

// ---------------- fallback path (round-1 passing kernel, 365us) ----------------
#define IT_OLD 32
#define BT_OLD 16

__global__ __launch_bounds__(256) void zero_kernel(float* __restrict__ p, int n) {
    int idx = blockIdx.x * blockDim.x + threadIdx.x;
    if (idx < n) p[idx] = 0.f;
}

__global__ __launch_bounds__(256) void squash_old(float* __restrict__ s_acc,
                                                  float* __restrict__ dst, float scale,
                                                  int add_to_dst, int zero_src) {
    int idx = blockIdx.x * blockDim.x + threadIdx.x;
    if (idx >= BB * JJ) return;
    float s[DD];
    float ss = 0.f;
#pragma unroll
    for (int d = 0; d < DD; ++d) {
        s[d] = s_acc[idx * DD + d] * scale;
        ss += s[d] * s[d];
    }
    const float coef = ss / (1.f + ss) / sqrtf(ss + 1e-7f);
#pragma unroll
    for (int d = 0; d < DD; ++d) {
        const float vv = coef * s[d];
        if (add_to_dst) dst[idx * DD + d] += vv;
        else            dst[idx * DD + d] = vv;
        if (zero_src)   s_acc[idx * DD + d] = 0.f;
    }
}

__global__ __launch_bounds__(256) void round1_old(const float* __restrict__ x,
                                                  const float* __restrict__ W,
                                                  float* __restrict__ s_acc) {
    const int t = threadIdx.x;
    const int d = t & 15;
    const int bq = t >> 4;
    const int b = blockIdx.y * BT_OLD + bq;
    const int i0 = blockIdx.x * IT_OLD;
    float acc[JJ];
#pragma unroll
    for (int j = 0; j < JJ; ++j) acc[j] = 0.f;
    for (int ii = 0; ii < IT_OLD; ++ii) {
        const int i = i0 + ii;
        const float* xp = x + ((b * II) + i) * KK;
        const float4 xa = *(const float4*)(xp);
        const float4 xb = *(const float4*)(xp + 4);
#pragma unroll
        for (int j = 0; j < JJ; ++j) {
            const float* wp = W + (((j * II + i) * DD + d) * KK);
            const float4 w0 = *(const float4*)(wp);
            const float4 w1 = *(const float4*)(wp + 4);
            acc[j] += w0.x*xa.x + w0.y*xa.y + w0.z*xa.z + w0.w*xa.w
                    + w1.x*xb.x + w1.y*xb.y + w1.z*xb.z + w1.w*xb.w;
        }
    }
#pragma unroll
    for (int j = 0; j < JJ; ++j)
        atomicAdd(&s_acc[(b * JJ + j) * DD + d], acc[j]);
}

__global__ __launch_bounds__(256) void round_old(const float* __restrict__ x,
                                                 const float* __restrict__ W,
                                                 const float* __restrict__ v,
                                                 float* __restrict__ s_acc) {
    const int t = threadIdx.x;
    const int d = t & 15;
    const int bq = t >> 4;
    const int b = blockIdx.y * BT_OLD + bq;
    const int i0 = blockIdx.x * IT_OLD;
    float vr[JJ], acc[JJ];
#pragma unroll
    for (int j = 0; j < JJ; ++j) {
        vr[j] = v[(b * JJ + j) * DD + d];
        acc[j] = 0.f;
    }
    for (int ii = 0; ii < IT_OLD; ++ii) {
        const int i = i0 + ii;
        const float* xp = x + ((b * II) + i) * KK;
        const float4 xa = *(const float4*)(xp);
        const float4 xb = *(const float4*)(xp + 4);
        float U[JJ], Lg[JJ];
#pragma unroll
        for (int j = 0; j < JJ; ++j) {
            const float* wp = W + (((j * II + i) * DD + d) * KK);
            const float4 w0 = *(const float4*)(wp);
            const float4 w1 = *(const float4*)(wp + 4);
            U[j] = w0.x*xa.x + w0.y*xa.y + w0.z*xa.z + w0.w*xa.w
                 + w1.x*xb.x + w1.y*xb.y + w1.z*xb.z + w1.w*xb.w;
            Lg[j] = vr[j] * U[j];
        }
#pragma unroll
        for (int m = 8; m >= 1; m >>= 1) {
#pragma unroll
            for (int j = 0; j < JJ; ++j) Lg[j] += __shfl_xor(Lg[j], m, 64);
        }
        float mx = Lg[0];
#pragma unroll
        for (int j = 1; j < JJ; ++j) mx = fmaxf(mx, Lg[j]);
        float sum = 0.f;
#pragma unroll
        for (int j = 0; j < JJ; ++j) { Lg[j] = __expf(Lg[j] - mx); sum += Lg[j]; }
        const float inv = 1.f / sum;
#pragma unroll
        for (int j = 0; j < JJ; ++j) acc[j] += (Lg[j] * inv) * U[j];
    }
#pragma unroll
    for (int j = 0; j < JJ; ++j)
        atomicAdd(&s_acc[(b * JJ + j) * DD + d], acc[j]);
}

extern "C" void kernel_launch(void* const* d_in, const int* in_sizes, int n_in,
                              void* d_out, int out_size, void* d_ws, size_t ws_size,
                              hipStream_t stream) {
    const float* x = (const float*)d_in[0];   // [B, I, K]
    const float* W = (const float*)d_in[1];   // [J, I, D, K]
    float* out = (float*)d_out;               // [B, J, D]

    unsigned* bar = (unsigned*)d_ws;                       // 16 u32 (64B)
    float* vT     = (float*)((char*)d_ws + 64);            // 40960 f32, layout [j][b][d]
    _Float16* p   = (_Float16*)(vT + BB * JJ * DD);        // 16*128*2560 f16
    short* xTb    = (short*)(p + (size_t)16 * 128 * 2560); // I*B*K bf16
    short* Wb     = xTb + (size_t)II * BB * KK;            // J*I*D*K bf16
    const size_t need = 64 + (size_t)(BB * JJ * DD) * 4
                      + (size_t)16 * 128 * 2560 * 2
                      + ((size_t)II * BB * KK + (size_t)JJ * II * DD * KK) * 2;

    if (ws_size >= need) {
        hipMemsetAsync(bar, 0, 64, stream);
        const float* xa = x; const float* Wa = W;
        short* xta = xTb; short* Wba = Wb;
        float* vta = vT; _Float16* pa = p; float* oa = out;
        unsigned* ba = bar;
        void* ka[8] = {(void*)&xa, (void*)&Wa, (void*)&xta, (void*)&Wba,
                       (void*)&vta, (void*)&pa, (void*)&oa, (void*)&ba};
        hipError_t e = hipLaunchCooperativeKernel((const void*)fused_all,
                                                  dim3(512), dim3(256), ka, 0, stream);
        if (e != hipSuccess) {
            (void)hipGetLastError();   // clear sticky error; fall back
            pre_kernel<<<1280 + 2048, 256, 0, stream>>>(x, W, xTb, Wb);
            dim3 rg(128, 4);
            dim3 sg(5, 16);
            round_mfma<0><<<rg, 256, 0, stream>>>(xTb, Wb, vT, p);
            rs_kernel<0><<<sg, 256, 0, stream>>>(p, vT, out, 0.1f);
            round_mfma<1><<<rg, 256, 0, stream>>>(xTb, Wb, vT, p);
            rs_kernel<1><<<sg, 256, 0, stream>>>(p, vT, out, 1.0f);
            round_mfma<1><<<rg, 256, 0, stream>>>(xTb, Wb, vT, p);
            rs_kernel<2><<<sg, 256, 0, stream>>>(p, vT, out, 1.0f);
        }
    } else {
        // fallback: round-1 passing path
        float* s_acc = (float*)d_ws;
        float* v_buf = s_acc + BB * JJ * DD;
        const int NS = BB * JJ * DD;
        dim3 rg(II / IT_OLD, BB / BT_OLD);
        zero_kernel<<<(NS + 255) / 256, 256, 0, stream>>>(s_acc, NS);
        round1_old<<<rg, 256, 0, stream>>>(x, W, s_acc);
        squash_old<<<(BB * JJ + 255) / 256, 256, 0, stream>>>(s_acc, v_buf, 0.1f, 0, 1);
        round_old<<<rg, 256, 0, stream>>>(x, W, v_buf, s_acc);
        squash_old<<<(BB * JJ + 255) / 256, 256, 0, stream>>>(s_acc, v_buf, 1.0f, 1, 1);
        round_old<<<rg, 256, 0, stream>>>(x, W, v_buf, s_acc);
        squash_old<<<(BB * JJ + 255) / 256, 256, 0, stream>>>(s_acc, out, 1.0f, 0, 0);
    }
}

// Round 7
// 144.600 us; speedup vs baseline: 4.4433x; 4.4433x over previous
//
#include <hip/hip_runtime.h>
#include <math.h>

// CapsuleLayer dynamic routing, fp32 in/out. B=256, I=2048, K=8, J=10, D=16.
// R11: back to the multi-kernel R6 champion (139.9us) structure; fusion via
// grid-wide barriers is dead (R9/R10: ~70-100us per sync on 8-XCD MI355X,
// both cg::grid.sync and custom atomic barrier; boundary ~10us is cheaper).
// R9/R10 counters proved rounds are LATENCY-bound (VALUBusy 5.5%, MfmaUtil 1%,
// HBM 3%): per-il softmax chain serializes with only 2 waves/SIMD. Fix: halve
// i-chunk 16->8 -> grid 256 chunks x 4 ytiles = 1024 blocks = 4 blocks/CU =
// 4 waves/SIMD (2x TLP). Single 28KB LDS buffer (no double-buffer pipeline --
// block TLP provides the overlap now). rs: 512 thr, 8 cg x 32 serial loads.
// Round core math unchanged (mfma_f32_16x16x32_bf16, C/D col=lane&15=b,
// row=(lane>>4)*4+reg=d; round 1 packs 4 i's into K=32; j-pair uint4 p;
// vT layout [j][b][d]).
//
// ws: vT f32[40960] | p f16[16*256*2560] | xTb bf16[I*B*K] | Wb bf16[J*I*D*K] (~35 MB)

#define BB 256
#define II 2048
#define KK 8
#define JJ 10
#define DD 16
#define CH 256   // i-chunks (8 i each)

typedef __attribute__((ext_vector_type(4))) float f32x4;
typedef __attribute__((ext_vector_type(8))) short short8;

__device__ __forceinline__ short f2bf(float f) {
    union { float f; unsigned u; } v; v.f = f;
    unsigned r = v.u + 0x7FFFu + ((v.u >> 16) & 1u);   // RNE
    return (short)(r >> 16);
}

// Fused preprocessing:
//   blocks [0,1280): W fp32 [j,i,d,k] -> Wb bf16 same layout (k contiguous).
//   blocks [1280,3328): x fp32 [b,i,k] -> xTb bf16 [i,b,k], LDS transpose tile.
__global__ __launch_bounds__(256) void pre_kernel(const float* __restrict__ x,
                                                  const float* __restrict__ W,
                                                  short* __restrict__ xTb,
                                                  short* __restrict__ Wb) {
    __shared__ float4 tile[8 * 66];
    const int t = threadIdx.x;
    const int bid = blockIdx.x;
    if (bid < 1280) {
        const int idx = bid * 256 + t;
        const float4* src = (const float4*)(W + (size_t)idx * 8);
        const float4 a = src[0], b = src[1];
        short8 o;
        o[0] = f2bf(a.x); o[1] = f2bf(a.y); o[2] = f2bf(a.z); o[3] = f2bf(a.w);
        o[4] = f2bf(b.x); o[5] = f2bf(b.y); o[6] = f2bf(b.z); o[7] = f2bf(b.w);
        *(short8*)(Wb + (size_t)idx * 8) = o;
    } else {
        const int bb = bid - 1280;
        const int b0 = (bb >> 8) * 32, i0 = (bb & 255) * 8;
        {
            const int lb = t >> 3, li = t & 7;
            const float4* src = (const float4*)(x + ((b0 + lb) * II + (i0 + li)) * KK);
            tile[li * 66 + lb * 2 + 0] = src[0];
            tile[li * 66 + lb * 2 + 1] = src[1];
        }
        __syncthreads();
        {
            const int ri = t >> 5, rb = t & 31;
            const float4 p0 = tile[ri * 66 + rb * 2 + 0];
            const float4 p1 = tile[ri * 66 + rb * 2 + 1];
            short8 o;
            o[0] = f2bf(p0.x); o[1] = f2bf(p0.y); o[2] = f2bf(p0.z); o[3] = f2bf(p0.w);
            o[4] = f2bf(p1.x); o[5] = f2bf(p1.y); o[6] = f2bf(p1.z); o[7] = f2bf(p1.w);
            *(short8*)(xTb + ((size_t)(i0 + ri) * BB + (b0 + rb)) * KK) = o;
        }
    }
}

// ---- staging: 28 segments of 1024B per 8-i chunk (20 W halves + 8 x rows) ----
// LDS layout (shorts): Wl[j][il][d][k] at j*1024+il*128+d*8 ; Xl at 10240+il*512+b*8
#define LBUF 14336   // shorts (28672 B) -- single buffer, 4 blocks/CU

__device__ __forceinline__ void seg_src_dst(int s, int i0, int b0,
                                            const short* __restrict__ xTb,
                                            const short* __restrict__ Wb,
                                            const short** src, int* dst) {
    if (s < 20) {
        const int j = s >> 1, h = s & 1;
        *src = Wb + ((size_t)(j * II + i0) * DD) * KK + h * 512;
        *dst = j * 1024 + h * 512;
    } else {
        const int il = s - 20;
        *src = xTb + ((size_t)(i0 + il) * BB + b0) * KK;
        *dst = 10240 + il * 512;
    }
}

// One routing round. grid (256 chunks, 4 ytiles) = 1024 blocks, block 256
// (4 waves = 4 b-tiles of 16). Each block: one 8-i chunk, single LDS buffer.
// Partials p[bt][chunk][jp*64+lane] as uint4 (j-pair x 4 fp16).
template <int USE_C>
__global__ __launch_bounds__(256) void round_mfma(
    const short* __restrict__ xTb, const short* __restrict__ Wb,
    const float* __restrict__ vT, _Float16* __restrict__ p)
{
    __shared__ short L[LBUF];
    const int t = threadIdx.x;
    const int lane = t & 63, wv = t >> 6;
    const int col = lane & 15, q = lane >> 4;
    const int chunk = blockIdx.x;
    const int ytile = blockIdx.y;
    const int b0 = ytile * 64;
    const int bl = wv * 16 + col;          // b within block for this wave's tile
    const int i0 = chunk * 8;

    // ---- one-shot stage: 28 segments, 4 waves interleave ----
    short8 r0[7];
#pragma unroll
    for (int n = 0; n < 7; ++n) {
        const int s = wv + n * 4;
        const short* src; int dst;
        seg_src_dst(s, i0, b0, xTb, Wb, &src, &dst);
        r0[n] = *(const short8*)(src + lane * 8);
    }
#pragma unroll
    for (int n = 0; n < 7; ++n) {
        const int s = wv + n * 4;
        const short* src; int dst;
        seg_src_dst(s, i0, b0, xTb, Wb, &src, &dst);
        *(short8*)(&L[dst + lane * 8]) = r0[n];
    }
    __syncthreads();

    f32x4 sfrag[JJ];
#pragma unroll
    for (int j = 0; j < JJ; ++j) sfrag[j] = (f32x4){0.f, 0.f, 0.f, 0.f};

    if (USE_C) {
        f32x4 vfrag[JJ];
#pragma unroll
        for (int j = 0; j < JJ; ++j)
            vfrag[j] = *(const f32x4*)(vT + ((size_t)j * BB + b0 + bl) * DD + q * 4);

        for (int il = 0; il < 8; ++il) {
            short8 A[JJ], Bf;
            const short8 z = (short8){0, 0, 0, 0, 0, 0, 0, 0};
            Bf = z;
#pragma unroll
            for (int j = 0; j < JJ; ++j) A[j] = z;
            if (q == 0) {   // kc 0..7 real, quads 1..3 stay zero (k-pad 8->32)
                Bf = *(const short8*)(&L[10240 + il * 512 + bl * 8]);
#pragma unroll
                for (int j = 0; j < JJ; ++j)
                    A[j] = *(const short8*)(&L[j * 1024 + il * 128 + col * 8]);
            }
            f32x4 U[JJ];
#pragma unroll
            for (int j = 0; j < JJ; ++j)
                U[j] = __builtin_amdgcn_mfma_f32_16x16x32_bf16(
                    A[j], Bf, (f32x4){0.f, 0.f, 0.f, 0.f}, 0, 0, 0);
            float Lg[JJ];
#pragma unroll
            for (int j = 0; j < JJ; ++j)
                Lg[j] = vfrag[j][0] * U[j][0] + vfrag[j][1] * U[j][1]
                      + vfrag[j][2] * U[j][2] + vfrag[j][3] * U[j][3];
#pragma unroll
            for (int j = 0; j < JJ; ++j) {   // reduce over the 4 d-quads
                Lg[j] += __shfl_xor(Lg[j], 16, 64);
                Lg[j] += __shfl_xor(Lg[j], 32, 64);
            }
            float sum = 0.f;   // |logit| is O(1): no max-subtraction needed
#pragma unroll
            for (int j = 0; j < JJ; ++j) { Lg[j] = __expf(Lg[j]); sum += Lg[j]; }
            const float inv = __builtin_amdgcn_rcpf(sum);
#pragma unroll
            for (int j = 0; j < JJ; ++j) {
                const float c = Lg[j] * inv;
#pragma unroll
                for (int r = 0; r < 4; ++r) sfrag[j][r] += c * U[j][r];
            }
        }
    } else {
        // round 1: sum_i U. Pack 4 i's per MFMA: kc = q*8 + k -> i_local = q.
#pragma unroll
        for (int s = 0; s < 2; ++s) {
            const int il = s * 4 + q;
            const short8 Bf = *(const short8*)(&L[10240 + il * 512 + bl * 8]);
#pragma unroll
            for (int j = 0; j < JJ; ++j) {
                const short8 A = *(const short8*)(&L[j * 1024 + il * 128 + col * 8]);
                sfrag[j] = __builtin_amdgcn_mfma_f32_16x16x32_bf16(A, Bf, sfrag[j], 0, 0, 0);
            }
        }
    }

    // epilogue: j-pair-packed fp16, 5 coalesced 16B stores per lane
    _Float16* pp = p + (((size_t)(ytile * 4 + wv) * CH + chunk) * 5) * 512;
#pragma unroll
    for (int jp = 0; jp < 5; ++jp) {
        union { uint4 u; _Float16 h[8]; } pk;
        pk.h[0] = (_Float16)sfrag[2 * jp][0];
        pk.h[1] = (_Float16)sfrag[2 * jp][1];
        pk.h[2] = (_Float16)sfrag[2 * jp][2];
        pk.h[3] = (_Float16)sfrag[2 * jp][3];
        pk.h[4] = (_Float16)sfrag[2 * jp + 1][0];
        pk.h[5] = (_Float16)sfrag[2 * jp + 1][1];
        pk.h[6] = (_Float16)sfrag[2 * jp + 1][2];
        pk.h[7] = (_Float16)sfrag[2 * jp + 1][3];
        *(uint4*)(pp + (size_t)(jp * 64 + lane) * 8) = pk.u;
    }
}

// Fused reduce + squash. grid (5 jp, 16 bt), block 512 = 64 elem-groups x 8
// chunk-groups. Thread (eg,cg) sums 32 chunks of a 16B (8 fp16 = 2 j's) slot ->
// LDS combine 8 cgs -> t<64 squashes both j's in-register (shfl over d-quads).
// MODE 0: vT = squash(scale*s)   MODE 1: vT += squash(s)   MODE 2: out = squash(s)
// vT layout: [j][b][d] (f32x4-friendly).
template <int MODE>
__global__ __launch_bounds__(512) void rs_kernel(const _Float16* __restrict__ p,
                                                 float* __restrict__ vT,
                                                 float* __restrict__ out, float scale) {
    __shared__ float red[512][9];
    const int t = threadIdx.x;
    const int jp = blockIdx.x, bt = blockIdx.y;
    const int eg = t & 63, cg = t >> 6;

    const _Float16* pp = p + (((size_t)bt * CH + cg * 32) * 5 + jp) * 512 + eg * 8;
    float s[8];
#pragma unroll
    for (int r = 0; r < 8; ++r) s[r] = 0.f;
#pragma unroll 8
    for (int ch = 0; ch < 32; ++ch) {
        union { uint4 u; _Float16 h[8]; } cv;
        cv.u = *(const uint4*)(pp + (size_t)ch * (5 * 512));
#pragma unroll
        for (int r = 0; r < 8; ++r) s[r] += (float)cv.h[r];
    }
#pragma unroll
    for (int r = 0; r < 8; ++r) red[t][r] = s[r];
    __syncthreads();
    if (t < 64) {
        float a[8];
#pragma unroll
        for (int r = 0; r < 8; ++r) {
            float acc = red[t][r];
#pragma unroll
            for (int g = 1; g < 8; ++g) acc += red[t + 64 * g][r];
            a[r] = acc;
        }
        const int qd = t >> 4, bc = t & 15;
#pragma unroll
        for (int jj = 0; jj < 2; ++jj) {
            const int j = jp * 2 + jj;
            const float x0 = a[jj * 4 + 0] * scale, x1 = a[jj * 4 + 1] * scale;
            const float x2 = a[jj * 4 + 2] * scale, x3 = a[jj * 4 + 3] * scale;
            float ss = x0 * x0 + x1 * x1 + x2 * x2 + x3 * x3;
            ss += __shfl_xor(ss, 16, 64);   // sum over the 4 d-quads (same bc)
            ss += __shfl_xor(ss, 32, 64);
            const float coef = ss / (1.f + ss) / sqrtf(ss + 1e-7f);
            f32x4 v = {coef * x0, coef * x1, coef * x2, coef * x3};
            if (MODE == 0)
                *(f32x4*)(vT + ((size_t)j * BB + bt * 16 + bc) * DD + qd * 4) = v;
            if (MODE == 1) {
                f32x4 o = *(f32x4*)(vT + ((size_t)j * BB + bt * 16 + bc) * DD + qd * 4);
                o += v;
                *(f32x4*)(vT + ((size_t)j * BB + bt * 16 + bc) * DD + qd * 4) = o;
            }
            if (MODE == 2)
                *(f32x4*)(out + ((size_t)(bt * 16 + bc) * JJ + j) * DD + qd * 4) = v;
        }
    }
}

// ---------------- fallback path (round-1 passing kernel, 365us) ----------------
#define IT_OLD 32
#define BT_OLD 16

__global__ __launch_bounds__(256) void zero_kernel(float* __restrict__ p, int n) {
    int idx = blockIdx.x * blockDim.x + threadIdx.x;
    if (idx < n) p[idx] = 0.f;
}

__global__ __launch_bounds__(256) void squash_old(float* __restrict__ s_acc,
                                                  float* __restrict__ dst, float scale,
                                                  int add_to_dst, int zero_src) {
    int idx = blockIdx.x * blockDim.x + threadIdx.x;
    if (idx >= BB * JJ) return;
    float s[DD];
    float ss = 0.f;
#pragma unroll
    for (int d = 0; d < DD; ++d) {
        s[d] = s_acc[idx * DD + d] * scale;
        ss += s[d] * s[d];
    }
    const float coef = ss / (1.f + ss) / sqrtf(ss + 1e-7f);
#pragma unroll
    for (int d = 0; d < DD; ++d) {
        const float vv = coef * s[d];
        if (add_to_dst) dst[idx * DD + d] += vv;
        else            dst[idx * DD + d] = vv;
        if (zero_src)   s_acc[idx * DD + d] = 0.f;
    }
}

__global__ __launch_bounds__(256) void round1_old(const float* __restrict__ x,
                                                  const float* __restrict__ W,
                                                  float* __restrict__ s_acc) {
    const int t = threadIdx.x;
    const int d = t & 15;
    const int bq = t >> 4;
    const int b = blockIdx.y * BT_OLD + bq;
    const int i0 = blockIdx.x * IT_OLD;
    float acc[JJ];
#pragma unroll
    for (int j = 0; j < JJ; ++j) acc[j] = 0.f;
    for (int ii = 0; ii < IT_OLD; ++ii) {
        const int i = i0 + ii;
        const float* xp = x + ((b * II) + i) * KK;
        const float4 xa = *(const float4*)(xp);
        const float4 xb = *(const float4*)(xp + 4);
#pragma unroll
        for (int j = 0; j < JJ; ++j) {
            const float* wp = W + (((j * II + i) * DD + d) * KK);
            const float4 w0 = *(const float4*)(wp);
            const float4 w1 = *(const float4*)(wp + 4);
            acc[j] += w0.x*xa.x + w0.y*xa.y + w0.z*xa.z + w0.w*xa.w
                    + w1.x*xb.x + w1.y*xb.y + w1.z*xb.z + w1.w*xb.w;
        }
    }
#pragma unroll
    for (int j = 0; j < JJ; ++j)
        atomicAdd(&s_acc[(b * JJ + j) * DD + d], acc[j]);
}

__global__ __launch_bounds__(256) void round_old(const float* __restrict__ x,
                                                 const float* __restrict__ W,
                                                 const float* __restrict__ v,
                                                 float* __restrict__ s_acc) {
    const int t = threadIdx.x;
    const int d = t & 15;
    const int bq = t >> 4;
    const int b = blockIdx.y * BT_OLD + bq;
    const int i0 = blockIdx.x * IT_OLD;
    float vr[JJ], acc[JJ];
#pragma unroll
    for (int j = 0; j < JJ; ++j) {
        vr[j] = v[(b * JJ + j) * DD + d];
        acc[j] = 0.f;
    }
    for (int ii = 0; ii < IT_OLD; ++ii) {
        const int i = i0 + ii;
        const float* xp = x + ((b * II) + i) * KK;
        const float4 xa = *(const float4*)(xp);
        const float4 xb = *(const float4*)(xp + 4);
        float U[JJ], Lg[JJ];
#pragma unroll
        for (int j = 0; j < JJ; ++j) {
            const float* wp = W + (((j * II + i) * DD + d) * KK);
            const float4 w0 = *(const float4*)(wp);
            const float4 w1 = *(const float4*)(wp + 4);
            U[j] = w0.x*xa.x + w0.y*xa.y + w0.z*xa.z + w0.w*xa.w
                 + w1.x*xb.x + w1.y*xb.y + w1.z*xb.z + w1.w*xb.w;
            Lg[j] = vr[j] * U[j];
        }
#pragma unroll
        for (int m = 8; m >= 1; m >>= 1) {
#pragma unroll
            for (int j = 0; j < JJ; ++j) Lg[j] += __shfl_xor(Lg[j], m, 64);
        }
        float mx = Lg[0];
#pragma unroll
        for (int j = 1; j < JJ; ++j) mx = fmaxf(mx, Lg[j]);
        float sum = 0.f;
#pragma unroll
        for (int j = 0; j < JJ; ++j) { Lg[j] = __expf(Lg[j] - mx); sum += Lg[j]; }
        const float inv = 1.f / sum;
#pragma unroll
        for (int j = 0; j < JJ; ++j) acc[j] += (Lg[j] * inv) * U[j];
    }
#pragma unroll
    for (int j = 0; j < JJ; ++j)
        atomicAdd(&s_acc[(b * JJ + j) * DD + d], acc[j]);
}

extern "C" void kernel_launch(void* const* d_in, const int* in_sizes, int n_in,
                              void* d_out, int out_size, void* d_ws, size_t ws_size,
                              hipStream_t stream) {
    const float* x = (const float*)d_in[0];   // [B, I, K]
    const float* W = (const float*)d_in[1];   // [J, I, D, K]
    float* out = (float*)d_out;               // [B, J, D]

    float* vT     = (float*)d_ws;                         // 40960 f32, layout [j][b][d]
    _Float16* p   = (_Float16*)(vT + BB * JJ * DD);       // 16*CH*2560 f16
    short* xTb    = (short*)(p + (size_t)16 * CH * 2560); // I*B*K bf16
    short* Wb     = xTb + (size_t)II * BB * KK;           // J*I*D*K bf16
    const size_t need = (size_t)(BB * JJ * DD) * 4
                      + (size_t)16 * CH * 2560 * 2
                      + ((size_t)II * BB * KK + (size_t)JJ * II * DD * KK) * 2;

    if (ws_size >= need) {
        pre_kernel<<<1280 + 2048, 256, 0, stream>>>(x, W, xTb, Wb);

        dim3 rg(CH, 4);
        dim3 sg(5, 16);
        // round 1: uniform c (1/J folded into squash scale)
        round_mfma<0><<<rg, 256, 0, stream>>>(xTb, Wb, vT, p);
        rs_kernel<0><<<sg, 512, 0, stream>>>(p, vT, out, 0.1f);
        // round 2: logits = v1 . U
        round_mfma<1><<<rg, 256, 0, stream>>>(xTb, Wb, vT, p);
        rs_kernel<1><<<sg, 512, 0, stream>>>(p, vT, out, 1.0f);
        // round 3: logits = (v1+v2) . U
        round_mfma<1><<<rg, 256, 0, stream>>>(xTb, Wb, vT, p);
        rs_kernel<2><<<sg, 512, 0, stream>>>(p, vT, out, 1.0f);
    } else {
        // fallback: round-1 passing path
        float* s_acc = (float*)d_ws;
        float* v_buf = s_acc + BB * JJ * DD;
        const int NS = BB * JJ * DD;
        dim3 rg(II / IT_OLD, BB / BT_OLD);
        zero_kernel<<<(NS + 255) / 256, 256, 0, stream>>>(s_acc, NS);
        round1_old<<<rg, 256, 0, stream>>>(x, W, s_acc);
        squash_old<<<(BB * JJ + 255) / 256, 256, 0, stream>>>(s_acc, v_buf, 0.1f, 0, 1);
        round_old<<<rg, 256, 0, stream>>>(x, W, v_buf, s_acc);
        squash_old<<<(BB * JJ + 255) / 256, 256, 0, stream>>>(s_acc, v_buf, 1.0f, 1, 1);
        round_old<<<rg, 256, 0, stream>>>(x, W, v_buf, s_acc);
        squash_old<<<(BB * JJ + 255) / 256, 256, 0, stream>>>(s_acc, out, 1.0f, 0, 0);
    }
}